// Round 3
// baseline (62.712 us; speedup 1.0000x reference)
//
#include <hip/hip_runtime.h>
#include <hip/hip_cooperative_groups.h>
#include <math.h>

namespace cg = cooperative_groups;

#define Sd 52
#define SS (Sd*Sd)      // 2704
#define Cc 80
#define NCc 85
#define NCH 255
#define Bb 64
#define Mm 50
#define DIVc 8.0f
#define KB 8                    // blocks per batch
#define NBLK (Bb*KB)            // 512
#define BCE_TOT (Mm*Cc)         // 4000
#define BCE_SH  (BCE_TOT/KB)    // 500
#define NO_TOT  (3*SS)          // 8112
#define NO_SH   (NO_TOT/KB)     // 1014

__device__ __constant__ float AW[9] = {10.f,16.f,33.f,30.f,62.f,59.f,116.f,156.f,373.f};
__device__ __constant__ float AH[9] = {13.f,30.f,23.f,61.f,45.f,119.f,90.f,198.f,326.f};

struct Dec {
    int   idx, valid, off;
    float ax, ay, w, h;
};

// Reference's quirky anchor IoU + cell decode; pure function of geo[b,m].
__device__ __forceinline__ Dec decode(const float* __restrict__ geo, int b, int m) {
    Dec d;
    const float cx = geo[(b*Mm+m)*4+0];
    const float cy = geo[(b*Mm+m)*4+1];
    const float w  = geo[(b*Mm+m)*4+2];
    const float h  = geo[(b*Mm+m)*4+3];
    // A=(aw+1)(ah+1), Bv=(w+1)(h+1), CM=(min(aw,w)+1)*(min(ah,h)-1)
    const float Bv = (w+1.f)*(h+1.f);
    float best = -INFINITY; int idx = 0;
    #pragma unroll
    for (int i = 0; i < 9; ++i) {
        const float A  = (AW[i]+1.f)*(AH[i]+1.f);
        const float CM = (fminf(AW[i],w)+1.f)*(fminf(AH[i],h)-1.f);
        const float iou = CM/(A+Bv-CM);
        if (iou > best) { best = iou; idx = i; }   // first-max tie-break
    }
    const int now = idx < 2 ? idx : 2;
    int ix = (int)(cx * (1.f/DIVc)); ix = ix < 0 ? 0 : (ix > Sd-1 ? Sd-1 : ix);
    int iy = (int)(cy * (1.f/DIVc)); iy = iy < 0 ? 0 : (iy > Sd-1 ? Sd-1 : iy);
    d.idx = idx;
    d.valid = (idx <= 2) ? 1 : 0;
    d.off = ((b*NCH + now*NCc)*Sd + ix)*Sd + iy;
    d.ax = (cx - (float)ix*DIVc) * (1.f/DIVc);
    d.ay = (cy - (float)iy*DIVc) * (1.f/DIVc);
    d.w = w; d.h = h;
    return d;
}

__global__ __launch_bounds__(256, 2) void yolo_all(
    const float* __restrict__ x,     // (B, 255, 52, 52)
    const float* __restrict__ geo,   // (B, 50, 4)
    const int*   __restrict__ cls,   // (B, 50)
    float* __restrict__ out,         // (1,)
    float* __restrict__ partial)     // (NBLK,) in d_ws
{
    const int blk = blockIdx.x;
    const int b   = blk >> 3;        // blk / KB
    const int k   = blk & (KB-1);
    const int tid = threadIdx.x;

    __shared__ unsigned char removed[NO_TOT];    // 8112 B bitmap (now, s1, s2)
    __shared__ float wf[4], wn[4];
    __shared__ int   wc[4];

    // ===== A: issue ALL global loads up front (overlap with LDS work) =====
    // BCE pair 0 (always) and pair 1 (tid < 244): re-decode box per thread,
    // independent of phase 1 -> no barrier before these scattered loads.
    const int t0 = k*BCE_SH + tid;
    const int m0 = t0 / Cc, c0 = t0 - m0*Cc;
    const Dec d0 = decode(geo, b, m0);
    const int cls0 = cls[b*Mm+m0];
    float v0 = 0.f;
    if (d0.valid) v0 = x[d0.off + (5+c0)*SS];

    const int has1 = (tid < BCE_SH - 256);
    const int t1 = t0 + 256;
    const int m1 = t1 / Cc, c1 = t1 - m1*Cc;
    Dec d1; d1.valid = 0; int cls1 = 0; float v1 = 0.f;
    if (has1) {
        d1 = decode(geo, b, m1);
        cls1 = cls[b*Mm+m1];
        if (d1.valid) v1 = x[d1.off + (5+c1)*SS];
    }

    // noobj preloads (coalesced, 3-4 per thread)
    const float* xb = x + (size_t)b*NCH*SS;
    float pre[4];
    #pragma unroll
    for (int i = 0; i < 4; ++i) {
        const int t = k*NO_SH + tid + i*256;
        float xv = 0.f;
        if (t < (k+1)*NO_SH) {
            const int nw = t / SS, s = t - nw*SS;
            xv = xb[nw*NCc*SS + s];
        }
        pre[i] = xv;
    }

    // ===== zero bitmap =====
    unsigned int* rem32 = (unsigned int*)removed;
    for (int i = tid; i < NO_TOT/4; i += 256) rem32[i] = 0u;
    __syncthreads();

    float lsum = 0.f;

    // ===== Phase 1: mark bitmap; coord loss once per batch (k==0) =====
    if (tid < Mm) {
        const Dec d = decode(geo, b, tid);
        const int now = d.idx < 2 ? d.idx : 2;
        if (d.valid) {
            removed[d.off - ((b*NCH + now*NCc)*SS)] = 1;  // = now*?? no; recompute below
        }
    }
    // NOTE: removed index must be now*SS + ix*Sd + iy; recompute cleanly:
    if (tid < Mm) {
        const Dec d = decode(geo, b, tid);
        const int now = d.idx < 2 ? d.idx : 2;
        const int cell = d.off - (b*NCH + now*NCc)*SS;    // ix*Sd + iy
        if (d.valid) removed[now*SS + cell] = 1;

        if (k == 0 && d.valid) {
            const float obj = x[d.off];
            const float e1  = x[d.off + 1*SS];
            const float e2  = x[d.off + 2*SS];
            const float e3  = x[d.off + 3*SS];
            const float e4  = x[d.off + 4*SS];

            const float rax = 1.f/(1.f+expf(-e1));
            const float ray = 1.f/(1.f+expf(-e2));
            const float rw  = AW[d.idx]*expf(e3);
            const float rh  = AH[d.idx]*expf(e4);

            const float X1 = rax*DIVc - rw*0.5f, Y1 = ray*DIVc - rh*0.5f;
            const float X2 = rax*DIVc + rw*0.5f, Y2 = ray*DIVc + rh*0.5f;
            const float x1 = d.ax*DIVc - d.w*0.5f, y1 = d.ay*DIVc - d.h*0.5f;
            const float x2 = d.ax*DIVc + d.w*0.5f, y2 = d.ay*DIVc + d.h*0.5f;
            const float Bv  = (d.w+1.f)*(d.h+1.f);
            const float A2  = (rw+1.f)*(rh+1.f);
            const float CM2 = (fminf(X2,x2)-fmaxf(X1,x1)+1.f) *
                              (fminf(Y2,y2)-fmaxf(Y1,y1+1.f));
            const float iou_t = CM2/(A2+Bv-CM2);

            const float q0 = obj-iou_t, q1 = rax-d.ax, q2 = ray-d.ay,
                        q3 = rw-d.w,   q4 = rh-d.h;
            lsum += 5.f*q0*q0 + q1*q1 + q2*q2 + q3*q3 + q4*q4;
        }
    }

    // ===== Phase 2: BCE from preloaded v0/v1 (no dependency on phase 1) =====
    if (d0.valid) {
        const float label = 1.f/(1.f+expf(-v0));
        const float term = (cls0 == c0) ? fmaxf(logf(label), -100.f)
                                        : fmaxf(log1pf(-label), -100.f);
        lsum -= term * (1.f/(float)Cc);
    }
    if (has1 && d1.valid) {
        const float label = 1.f/(1.f+expf(-v1));
        const float term = (cls1 == c1) ? fmaxf(logf(label), -100.f)
                                        : fmaxf(log1pf(-label), -100.f);
        lsum -= term * (1.f/(float)Cc);
    }

    __syncthreads();   // bitmap complete

    // ===== Phase 3: noobj num (preloaded) + full-bitmap count =====
    float num = 0.f;
    #pragma unroll
    for (int i = 0; i < 4; ++i) {
        const int t = k*NO_SH + tid + i*256;
        if (t < (k+1)*NO_SH && !removed[t]) num += pre[i]*pre[i];
    }
    int cnt = 0;
    for (int i = tid; i < NO_TOT/4; i += 256) {
        const unsigned int wd = rem32[i];
        cnt += (int)((wd * 0x01010101u) >> 24);       // sum of 4 bytes (0/1)
    }

    // ===== block reduce via shuffles =====
    #pragma unroll
    for (int o = 32; o > 0; o >>= 1) {
        lsum += __shfl_down(lsum, o);
        num  += __shfl_down(num,  o);
        cnt  += __shfl_down(cnt,  o);
    }
    if ((tid & 63) == 0) { wf[tid>>6] = lsum; wn[tid>>6] = num; wc[tid>>6] = cnt; }
    __syncthreads();
    if (tid == 0) {
        const float F  = wf[0]+wf[1]+wf[2]+wf[3];
        const float Nn = wn[0]+wn[1]+wn[2]+wn[3];
        const int   Ct = wc[0]+wc[1]+wc[2]+wc[3];
        partial[blk] = F + 0.5f * Nn / (float)(NO_TOT - Ct);
    }

    // ===== grid-wide reduction, single dispatch =====
    cg::this_grid().sync();
    if (blk == 0) {
        float v = partial[tid] + partial[tid + 256];
        #pragma unroll
        for (int o = 32; o > 0; o >>= 1) v += __shfl_down(v, o);
        if ((tid & 63) == 0) wf[tid>>6] = v;
        __syncthreads();
        if (tid == 0) out[0] = wf[0]+wf[1]+wf[2]+wf[3];
    }
}

extern "C" void kernel_launch(void* const* d_in, const int* in_sizes, int n_in,
                              void* d_out, int out_size, void* d_ws, size_t ws_size,
                              hipStream_t stream) {
    const float* x   = (const float*)d_in[0];
    const float* geo = (const float*)d_in[1];
    const int*   cls = (const int*)d_in[2];
    float* out     = (float*)d_out;
    float* partial = (float*)d_ws;     // NBLK floats

    void* args[] = { (void*)&x, (void*)&geo, (void*)&cls, (void*)&out, (void*)&partial };
    hipLaunchCooperativeKernel((void*)yolo_all, dim3(NBLK), dim3(256),
                               args, 0, stream);
}

// Round 4
// 25.213 us; speedup vs baseline: 2.4872x; 2.4872x over previous
//
#include <hip/hip_runtime.h>
#include <math.h>

#define Sd 52
#define SS (Sd*Sd)      // 2704
#define Cc 80
#define NCc 85
#define NCH 255
#define Bb 64
#define Mm 50
#define DIVc 8.0f
#define KB 8                    // blocks per batch
#define NBLK (Bb*KB)            // 512
#define BCE_SH  ((Mm*Cc)/KB)    // 500
#define NO_TOT  (3*SS)          // 8112
#define NO_SH   (NO_TOT/KB)     // 1014

__device__ __constant__ float AW[9] = {10.f,16.f,33.f,30.f,62.f,59.f,116.f,156.f,373.f};
__device__ __constant__ float AH[9] = {13.f,30.f,23.f,61.f,45.f,119.f,90.f,198.f,326.f};

struct Dec {
    int   idx, valid, now, cell, off;
    float ax, ay, w, h;
};

// Reference's quirky anchor IoU + cell decode; pure function of geo[b,m].
__device__ __forceinline__ Dec decode(const float4* __restrict__ geo4, int b, int m) {
    Dec d;
    const float4 g = geo4[b*Mm + m];
    const float cx = g.x, cy = g.y, w = g.z, h = g.w;
    // A=(aw+1)(ah+1), Bv=(w+1)(h+1), CM=(min(aw,w)+1)*(min(ah,h)-1)
    const float Bv = (w+1.f)*(h+1.f);
    float best = -INFINITY; int idx = 0;
    #pragma unroll
    for (int i = 0; i < 9; ++i) {
        const float A  = (AW[i]+1.f)*(AH[i]+1.f);
        const float CM = (fminf(AW[i],w)+1.f)*(fminf(AH[i],h)-1.f);
        const float iou = CM/(A+Bv-CM);
        if (iou > best) { best = iou; idx = i; }   // first-max tie-break
    }
    d.idx   = idx;
    d.valid = (idx <= 2) ? 1 : 0;
    d.now   = idx < 2 ? idx : 2;
    int ix = (int)(cx * 0.125f); ix = ix < 0 ? 0 : (ix > Sd-1 ? Sd-1 : ix);
    int iy = (int)(cy * 0.125f); iy = iy < 0 ? 0 : (iy > Sd-1 ? Sd-1 : iy);
    d.cell = ix*Sd + iy;
    d.off  = (b*NCH + d.now*NCc)*SS + d.cell;
    d.ax = (cx - (float)ix*DIVc) * 0.125f;
    d.ay = (cy - (float)iy*DIVc) * 0.125f;
    d.w = w; d.h = h;
    return d;
}

__global__ __launch_bounds__(256, 2) void yolo_fused(
    const float*  __restrict__ x,      // (B, 255, 52, 52)
    const float4* __restrict__ geo4,   // (B, 50) float4
    const int*    __restrict__ cls,    // (B, 50)
    float* __restrict__ out,           // (1,)
    float* __restrict__ partial,       // (NBLK,) in d_ws
    unsigned int* __restrict__ ctr)    // 1 uint in d_ws
{
    const int blk = blockIdx.x;
    const int b   = blk >> 3;
    const int k   = blk & (KB-1);
    const int tid = threadIdx.x;

    __shared__ unsigned char removed[NO_TOT];    // 8112 B bitmap (now, s1, s2)
    __shared__ float wsf[4], wsn[4];
    __shared__ int   wsc[4];
    __shared__ int   fin;

    // ===== issue ALL scattered global loads up front (latency overlap) =====
    // BCE pair 0: every thread re-decodes its own box (no barrier dependency).
    const int t0 = k*BCE_SH + tid;
    const int m0 = t0 / Cc, c0 = t0 - m0*Cc;
    const Dec d0 = decode(geo4, b, m0);
    const int cls0 = cls[b*Mm + m0];
    const float v0 = x[d0.off + (5+c0)*SS];          // in-bounds even if !valid

    // BCE pair 1 (tid < 244); clamp index for inactive lanes, mask at use.
    const bool has1 = tid < (BCE_SH - 256);
    const int t1 = t0 + 256;
    const int m1 = has1 ? t1 / Cc : m0;
    const int c1 = has1 ? (t1 - m1*Cc) : c0;
    const Dec d1 = decode(geo4, b, m1);
    const int cls1 = cls[b*Mm + m1];
    const float v1 = x[d1.off + (5+c1)*SS];

    // noobj preloads (coalesced, 4 per thread; only i=3 can be out-of-share)
    const float* xb = x + (size_t)b*NCH*SS;
    float pre[4]; int tix[4]; bool pm[4];
    #pragma unroll
    for (int i = 0; i < 4; ++i) {
        const int t = k*NO_SH + tid + i*256;
        pm[i]  = (t < (k+1)*NO_SH);
        tix[i] = pm[i] ? t : k*NO_SH;
        const int nw = tix[i] / SS, s = tix[i] - nw*SS;
        pre[i] = xb[nw*NCc*SS + s];
    }

    // phase-1 decode (tid<50) + coord-channel loads (k==0 blocks only)
    Dec dp; dp.valid = 0; dp.now = 0; dp.cell = 0;
    float e0=0.f, e1=0.f, e2=0.f, e3=0.f, e4=0.f;
    const bool p1 = (tid < Mm);
    if (p1) {
        dp = decode(geo4, b, tid);
        if (k == 0) {
            e0 = x[dp.off];
            e1 = x[dp.off + 1*SS];
            e2 = x[dp.off + 2*SS];
            e3 = x[dp.off + 3*SS];
            e4 = x[dp.off + 4*SS];
        }
    }

    // ===== zero bitmap while loads are in flight =====
    unsigned int* rem32 = (unsigned int*)removed;
    for (int i = tid; i < NO_TOT/4; i += 256) rem32[i] = 0u;
    __syncthreads();

    float lsum = 0.f;

    // ===== Phase 1: mark bitmap; coord loss once per batch (k==0) =====
    if (p1 && dp.valid) {
        removed[dp.now*SS + dp.cell] = 1;
        if (k == 0) {
            const float rax = 1.f/(1.f+expf(-e1));
            const float ray = 1.f/(1.f+expf(-e2));
            const float rw  = AW[dp.idx]*expf(e3);
            const float rh  = AH[dp.idx]*expf(e4);

            // iou_t with the reference's quirky formula (y1+1 inside the max)
            const float X1 = rax*DIVc - rw*0.5f, Y1 = ray*DIVc - rh*0.5f;
            const float X2 = rax*DIVc + rw*0.5f, Y2 = ray*DIVc + rh*0.5f;
            const float x1 = dp.ax*DIVc - dp.w*0.5f, y1 = dp.ay*DIVc - dp.h*0.5f;
            const float x2 = dp.ax*DIVc + dp.w*0.5f, y2 = dp.ay*DIVc + dp.h*0.5f;
            const float Bv  = (dp.w+1.f)*(dp.h+1.f);
            const float A2  = (rw+1.f)*(rh+1.f);
            const float CM2 = (fminf(X2,x2)-fmaxf(X1,x1)+1.f) *
                              (fminf(Y2,y2)-fmaxf(Y1,y1+1.f));
            const float iou_t = CM2/(A2+Bv-CM2);

            const float q0 = e0-iou_t, q1 = rax-dp.ax, q2 = ray-dp.ay,
                        q3 = rw-dp.w,  q4 = rh-dp.h;
            lsum += 5.f*q0*q0 + q1*q1 + q2*q2 + q3*q3 + q4*q4;
        }
    }

    // ===== Phase 2: BCE from prefetched v0/v1 (independent of bitmap) =====
    if (d0.valid) {
        const float label = 1.f/(1.f+expf(-v0));
        const float term = (cls0 == c0) ? fmaxf(logf(label),    -100.f)
                                        : fmaxf(log1pf(-label), -100.f);
        lsum -= term * (1.f/(float)Cc);
    }
    if (has1 && d1.valid) {
        const float label = 1.f/(1.f+expf(-v1));
        const float term = (cls1 == c1) ? fmaxf(logf(label),    -100.f)
                                        : fmaxf(log1pf(-label), -100.f);
        lsum -= term * (1.f/(float)Cc);
    }

    __syncthreads();   // bitmap complete

    // ===== Phase 3: noobj num (prefetched) + full-bitmap count =====
    float num = 0.f;
    #pragma unroll
    for (int i = 0; i < 4; ++i)
        if (pm[i] && !removed[tix[i]]) num += pre[i]*pre[i];

    int cnt = 0;
    for (int i = tid; i < NO_TOT/4; i += 256) {
        const unsigned int wd = rem32[i];
        cnt += (int)((wd * 0x01010101u) >> 24);       // sum of 4 bytes (0/1)
    }

    // ===== block reduce via shuffles =====
    #pragma unroll
    for (int o = 32; o > 0; o >>= 1) {
        lsum += __shfl_down(lsum, o);
        num  += __shfl_down(num,  o);
        cnt  += __shfl_down(cnt,  o);
    }
    const int wv = tid >> 6;
    if ((tid & 63) == 0) { wsf[wv] = lsum; wsn[wv] = num; wsc[wv] = cnt; }
    __syncthreads();
    if (tid == 0) {
        const float F  = wsf[0]+wsf[1]+wsf[2]+wsf[3];
        const float Nn = wsn[0]+wsn[1]+wsn[2]+wsn[3];
        const int   Ct = wsc[0]+wsc[1]+wsc[2]+wsc[3];
        const float pval = F + 0.5f * Nn / (float)(NO_TOT - Ct);
        // agent-scope store: visible across XCDs regardless of L2 state
        __hip_atomic_store(&partial[blk], pval, __ATOMIC_RELEASE,
                           __HIP_MEMORY_SCOPE_AGENT);
        __threadfence();
        // last-block detection via atomicInc wrap: cycle length 512.
        // Any start >=511 (0xAA poison / steady-state 511) behaves exactly;
        // old==NBLK-2 is seen only by the 512th incrementer.
        const unsigned old = atomicInc(ctr, NBLK-1u);
        fin = (old == (unsigned)(NBLK-2));
    }
    __syncthreads();

    // ===== finisher: deterministic fixed-order reduce of 512 partials =====
    if (fin && tid < 64) {
        __threadfence();
        float s = 0.f;
        #pragma unroll
        for (int i = 0; i < NBLK/64; ++i)
            s += __hip_atomic_load(&partial[tid + i*64], __ATOMIC_RELAXED,
                                   __HIP_MEMORY_SCOPE_AGENT);
        #pragma unroll
        for (int o = 32; o > 0; o >>= 1) s += __shfl_down(s, o);
        if (tid == 0) out[0] = s;
    }
}

extern "C" void kernel_launch(void* const* d_in, const int* in_sizes, int n_in,
                              void* d_out, int out_size, void* d_ws, size_t ws_size,
                              hipStream_t stream) {
    const float*  x    = (const float*)d_in[0];
    const float4* geo4 = (const float4*)d_in[1];
    const int*    cls  = (const int*)d_in[2];
    float* out     = (float*)d_out;
    float* partial = (float*)d_ws;                        // NBLK floats
    unsigned int* ctr = (unsigned int*)(partial + NBLK);  // 1 uint

    yolo_fused<<<NBLK, 256, 0, stream>>>(x, geo4, cls, out, partial, ctr);
}

// Round 5
// 20.898 us; speedup vs baseline: 3.0009x; 1.2065x over previous
//
#include <hip/hip_runtime.h>
#include <math.h>

#define Sd 52
#define SS (Sd*Sd)      // 2704
#define Cc 80
#define NCc 85
#define NCH 255
#define Bb 64
#define Mm 50
#define DIVc 8.0f
#define KB 8                    // blocks per batch
#define NBLK (Bb*KB)            // 512
#define BCE_SH  ((Mm*Cc)/KB)    // 500
#define NO_TOT  (3*SS)          // 8112
#define NO_SH   (NO_TOT/KB)     // 1014

__device__ __constant__ float AW[9] = {10.f,16.f,33.f,30.f,62.f,59.f,116.f,156.f,373.f};
__device__ __constant__ float AH[9] = {13.f,30.f,23.f,61.f,45.f,119.f,90.f,198.f,326.f};

struct Dec {
    int   idx, valid, now, cell, off;
    float ax, ay, w, h;
};

// Reference's quirky anchor IoU + cell decode; pure function of geo[b,m].
// Argmax via cross-multiplication (CM,D all > 0 here): no divides.
__device__ __forceinline__ Dec decode(const float4* __restrict__ geo4, int b, int m) {
    Dec d;
    const float4 g = geo4[b*Mm + m];
    const float cx = g.x, cy = g.y, w = g.z, h = g.w;
    // A=(aw+1)(ah+1), Bv=(w+1)(h+1), CM=(min(aw,w)+1)*(min(ah,h)-1), D=A+Bv-CM
    const float Bv = (w+1.f)*(h+1.f);
    float bCM = (fminf(AW[0],w)+1.f)*(fminf(AH[0],h)-1.f);
    float bD  = (AW[0]+1.f)*(AH[0]+1.f) + Bv - bCM;
    int idx = 0;
    #pragma unroll
    for (int i = 1; i < 9; ++i) {
        const float CM = (fminf(AW[i],w)+1.f)*(fminf(AH[i],h)-1.f);
        const float D  = (AW[i]+1.f)*(AH[i]+1.f) + Bv - CM;
        if (CM*bD > bCM*D) { bCM = CM; bD = D; idx = i; }  // first-max tie-break
    }
    d.idx   = idx;
    d.valid = (idx <= 2) ? 1 : 0;
    d.now   = idx < 2 ? idx : 2;
    int ix = (int)(cx * 0.125f); ix = ix < 0 ? 0 : (ix > Sd-1 ? Sd-1 : ix);
    int iy = (int)(cy * 0.125f); iy = iy < 0 ? 0 : (iy > Sd-1 ? Sd-1 : iy);
    d.cell = ix*Sd + iy;
    d.off  = (b*NCH + d.now*NCc)*SS + d.cell;
    d.ax = (cx - (float)ix*DIVc) * 0.125f;
    d.ay = (cy - (float)iy*DIVc) * 0.125f;
    d.w = w; d.h = h;
    return d;
}

__global__ __launch_bounds__(256, 2) void yolo_fused(
    const float*  __restrict__ x,      // (B, 255, 52, 52)
    const float4* __restrict__ geo4,   // (B, 50) float4
    const int*    __restrict__ cls,    // (B, 50)
    float* __restrict__ out)           // (1,) pre-zeroed by memset node
{
    const int blk = blockIdx.x;
    const int b   = blk >> 3;
    const int k   = blk & (KB-1);
    const int tid = threadIdx.x;

    __shared__ uint4 rem4[NO_TOT/16];            // 8112 B bitmap (now, s1, s2)
    unsigned char* removed = (unsigned char*)rem4;
    unsigned int*  rem32   = (unsigned int*)rem4;
    __shared__ float wsf[4], wsn[4];
    __shared__ int   wsc[4];

    // ===== issue ALL scattered global loads up front (latency overlap) =====
    // BCE pair 0: every thread re-decodes its own box (no barrier dependency).
    const int t0 = k*BCE_SH + tid;
    const int m0 = t0 / Cc, c0 = t0 - m0*Cc;
    const Dec d0 = decode(geo4, b, m0);
    const int cls0 = cls[b*Mm + m0];
    const float v0 = x[d0.off + (5+c0)*SS];          // in-bounds even if !valid

    // BCE pair 1 (tid < 244); clamp index for inactive lanes, mask at use.
    const bool has1 = tid < (BCE_SH - 256);
    const int t1 = t0 + 256;
    const int m1 = has1 ? t1 / Cc : m0;
    const int c1 = has1 ? (t1 - m1*Cc) : c0;
    const Dec d1 = decode(geo4, b, m1);
    const int cls1 = cls[b*Mm + m1];
    const float v1 = x[d1.off + (5+c1)*SS];

    // noobj preloads (coalesced, 4 per thread; only i=3 can be out-of-share)
    const float* xb = x + (size_t)b*NCH*SS;
    float pre[4]; int tix[4]; bool pm[4];
    #pragma unroll
    for (int i = 0; i < 4; ++i) {
        const int t = k*NO_SH + tid + i*256;
        pm[i]  = (t < (k+1)*NO_SH);
        tix[i] = pm[i] ? t : k*NO_SH;
        const int nw = tix[i] / SS, s = tix[i] - nw*SS;
        pre[i] = xb[nw*NCc*SS + s];
    }

    // phase-1 decode (tid<50) + coord-channel loads (k==0 blocks only)
    Dec dp; dp.valid = 0; dp.now = 0; dp.cell = 0; dp.idx = 0;
    float e0=0.f, e1=0.f, e2=0.f, e3=0.f, e4=0.f;
    const bool p1 = (tid < Mm);
    if (p1) {
        dp = decode(geo4, b, tid);
        if (k == 0) {
            e0 = x[dp.off];
            e1 = x[dp.off + 1*SS];
            e2 = x[dp.off + 2*SS];
            e3 = x[dp.off + 3*SS];
            e4 = x[dp.off + 4*SS];
        }
    }

    // ===== zero bitmap while loads are in flight (uint4: 2 iters) =====
    const uint4 z4 = {0u,0u,0u,0u};
    #pragma unroll
    for (int i = tid; i < NO_TOT/16; i += 256) rem4[i] = z4;
    __syncthreads();

    float lsum = 0.f;

    // ===== Phase 1: mark bitmap; coord loss once per batch (k==0) =====
    if (p1 && dp.valid) {
        removed[dp.now*SS + dp.cell] = 1;
        if (k == 0) {
            const float rax = 1.f/(1.f+expf(-e1));
            const float ray = 1.f/(1.f+expf(-e2));
            const float rw  = AW[dp.idx]*expf(e3);
            const float rh  = AH[dp.idx]*expf(e4);

            // iou_t with the reference's quirky formula (y1+1 inside the max)
            const float X1 = rax*DIVc - rw*0.5f, Y1 = ray*DIVc - rh*0.5f;
            const float X2 = rax*DIVc + rw*0.5f, Y2 = ray*DIVc + rh*0.5f;
            const float x1 = dp.ax*DIVc - dp.w*0.5f, y1 = dp.ay*DIVc - dp.h*0.5f;
            const float x2 = dp.ax*DIVc + dp.w*0.5f, y2 = dp.ay*DIVc + dp.h*0.5f;
            const float Bv  = (dp.w+1.f)*(dp.h+1.f);
            const float A2  = (rw+1.f)*(rh+1.f);
            const float CM2 = (fminf(X2,x2)-fmaxf(X1,x1)+1.f) *
                              (fminf(Y2,y2)-fmaxf(Y1,y1+1.f));
            const float iou_t = CM2/(A2+Bv-CM2);

            const float q0 = e0-iou_t, q1 = rax-dp.ax, q2 = ray-dp.ay,
                        q3 = rw-dp.w,  q4 = rh-dp.h;
            lsum += 5.f*q0*q0 + q1*q1 + q2*q2 + q3*q3 + q4*q4;
        }
    }

    // ===== Phase 2: BCE from prefetched v0/v1 (independent of bitmap) =====
    if (d0.valid) {
        const float label = 1.f/(1.f+expf(-v0));
        const float term = (cls0 == c0) ? fmaxf(logf(label),    -100.f)
                                        : fmaxf(log1pf(-label), -100.f);
        lsum -= term * (1.f/(float)Cc);
    }
    if (has1 && d1.valid) {
        const float label = 1.f/(1.f+expf(-v1));
        const float term = (cls1 == c1) ? fmaxf(logf(label),    -100.f)
                                        : fmaxf(log1pf(-label), -100.f);
        lsum -= term * (1.f/(float)Cc);
    }

    __syncthreads();   // bitmap complete

    // ===== Phase 3: noobj num (prefetched) + full-bitmap count =====
    float num = 0.f;
    #pragma unroll
    for (int i = 0; i < 4; ++i)
        if (pm[i] && !removed[tix[i]]) num += pre[i]*pre[i];

    int cnt = 0;
    #pragma unroll
    for (int i = tid; i < NO_TOT/16; i += 256) {
        const uint4 wd = rem4[i];
        const unsigned s = ((wd.x * 0x01010101u) >> 24)
                         + ((wd.y * 0x01010101u) >> 24)
                         + ((wd.z * 0x01010101u) >> 24)
                         + ((wd.w * 0x01010101u) >> 24);
        cnt += (int)s;
    }

    // ===== block reduce via shuffles =====
    #pragma unroll
    for (int o = 32; o > 0; o >>= 1) {
        lsum += __shfl_down(lsum, o);
        num  += __shfl_down(num,  o);
        cnt  += __shfl_down(cnt,  o);
    }
    const int wv = tid >> 6;
    if ((tid & 63) == 0) { wsf[wv] = lsum; wsn[wv] = num; wsc[wv] = cnt; }
    __syncthreads();
    if (tid == 0) {
        const float F  = wsf[0]+wsf[1]+wsf[2]+wsf[3];
        const float Nn = wsn[0]+wsn[1]+wsn[2]+wsn[3];
        const int   Ct = wsc[0]+wsc[1]+wsc[2]+wsc[3];
        atomicAdd(out, F + 0.5f * Nn / (float)(NO_TOT - Ct));
    }
}

extern "C" void kernel_launch(void* const* d_in, const int* in_sizes, int n_in,
                              void* d_out, int out_size, void* d_ws, size_t ws_size,
                              hipStream_t stream) {
    const float*  x    = (const float*)d_in[0];
    const float4* geo4 = (const float4*)d_in[1];
    const int*    cls  = (const int*)d_in[2];
    float* out = (float*)d_out;

    hipMemsetAsync(out, 0, sizeof(float), stream);
    yolo_fused<<<NBLK, 256, 0, stream>>>(x, geo4, cls, out);
}

// Round 6
// 15.255 us; speedup vs baseline: 4.1109x; 1.3699x over previous
//
#include <hip/hip_runtime.h>
#include <math.h>

#define Sd 52
#define SS (Sd*Sd)      // 2704
#define Cc 80
#define NCc 85
#define NCH 255
#define Bb 64
#define Mm 50
#define DIVc 8.0f
#define KB 8                    // blocks per batch
#define NBLK (Bb*KB)            // 512
#define BCE_SH  ((Mm*Cc)/KB)    // 500
#define NO_TOT  (3*SS)          // 8112
#define NO_SH   (NO_TOT/KB)     // 1014

__device__ __constant__ float AW[9] = {10.f,16.f,33.f,30.f,62.f,59.f,116.f,156.f,373.f};
__device__ __constant__ float AH[9] = {13.f,30.f,23.f,61.f,45.f,119.f,90.f,198.f,326.f};

struct Dec {
    int   idx, valid, now, cell, off;
    float ax, ay, w, h;
};

// Reference's quirky anchor IoU + cell decode; pure function of geo[b,m].
// Argmax via cross-multiplication (CM,D all > 0 for this data): no divides.
__device__ __forceinline__ Dec decode(const float4* __restrict__ geo4, int b, int m) {
    Dec d;
    const float4 g = geo4[b*Mm + m];
    const float cx = g.x, cy = g.y, w = g.z, h = g.w;
    // A=(aw+1)(ah+1), Bv=(w+1)(h+1), CM=(min(aw,w)+1)*(min(ah,h)-1), D=A+Bv-CM
    const float Bv = (w+1.f)*(h+1.f);
    float bCM = (fminf(AW[0],w)+1.f)*(fminf(AH[0],h)-1.f);
    float bD  = (AW[0]+1.f)*(AH[0]+1.f) + Bv - bCM;
    int idx = 0;
    #pragma unroll
    for (int i = 1; i < 9; ++i) {
        const float CM = (fminf(AW[i],w)+1.f)*(fminf(AH[i],h)-1.f);
        const float D  = (AW[i]+1.f)*(AH[i]+1.f) + Bv - CM;
        if (CM*bD > bCM*D) { bCM = CM; bD = D; idx = i; }  // first-max tie-break
    }
    d.idx   = idx;
    d.valid = (idx <= 2) ? 1 : 0;
    d.now   = idx < 2 ? idx : 2;
    int ix = (int)(cx * 0.125f); ix = ix < 0 ? 0 : (ix > Sd-1 ? Sd-1 : ix);
    int iy = (int)(cy * 0.125f); iy = iy < 0 ? 0 : (iy > Sd-1 ? Sd-1 : iy);
    d.cell = ix*Sd + iy;
    d.off  = (b*NCH + d.now*NCc)*SS + d.cell;
    d.ax = (cx - (float)ix*DIVc) * 0.125f;
    d.ay = (cy - (float)iy*DIVc) * 0.125f;
    d.w = w; d.h = h;
    return d;
}

__global__ __launch_bounds__(256, 2) void yolo_main(
    const float*  __restrict__ x,      // (B, 255, 52, 52)
    const float4* __restrict__ geo4,   // (B, 50) float4
    const int*    __restrict__ cls,    // (B, 50)
    float* __restrict__ partial)       // (NBLK,) in d_ws — fully overwritten
{
    const int blk = blockIdx.x;
    const int b   = blk >> 3;
    const int k   = blk & (KB-1);
    const int tid = threadIdx.x;

    __shared__ uint4 rem4[NO_TOT/16];            // 8112 B bitmap (now, s1, s2)
    unsigned char* removed = (unsigned char*)rem4;
    __shared__ float wsf[4], wsn[4];
    __shared__ int   wsc[4];

    // ===== issue ALL scattered global loads up front (latency overlap) =====
    // BCE pair 0: every thread re-decodes its own box (no barrier dependency).
    const int t0 = k*BCE_SH + tid;
    const int m0 = t0 / Cc, c0 = t0 - m0*Cc;
    const Dec d0 = decode(geo4, b, m0);
    const int cls0 = cls[b*Mm + m0];
    const float v0 = x[d0.off + (5+c0)*SS];          // in-bounds even if !valid

    // BCE pair 1 (tid < 244); clamp index for inactive lanes, mask at use.
    const bool has1 = tid < (BCE_SH - 256);
    const int t1 = t0 + 256;
    const int m1 = has1 ? t1 / Cc : m0;
    const int c1 = has1 ? (t1 - m1*Cc) : c0;
    const Dec d1 = decode(geo4, b, m1);
    const int cls1 = cls[b*Mm + m1];
    const float v1 = x[d1.off + (5+c1)*SS];

    // noobj preloads (coalesced, 4 per thread; only i=3 can be out-of-share)
    const float* xb = x + (size_t)b*NCH*SS;
    float pre[4]; int tix[4]; bool pm[4];
    #pragma unroll
    for (int i = 0; i < 4; ++i) {
        const int t = k*NO_SH + tid + i*256;
        pm[i]  = (t < (k+1)*NO_SH);
        tix[i] = pm[i] ? t : k*NO_SH;
        const int nw = tix[i] / SS, s = tix[i] - nw*SS;
        pre[i] = xb[nw*NCc*SS + s];
    }

    // phase-1 decode (tid<50) + coord-channel loads (k==0 blocks only)
    Dec dp; dp.valid = 0; dp.now = 0; dp.cell = 0; dp.idx = 0;
    float e0=0.f, e1=0.f, e2=0.f, e3=0.f, e4=0.f;
    const bool p1 = (tid < Mm);
    if (p1) {
        dp = decode(geo4, b, tid);
        if (k == 0) {
            e0 = x[dp.off];
            e1 = x[dp.off + 1*SS];
            e2 = x[dp.off + 2*SS];
            e3 = x[dp.off + 3*SS];
            e4 = x[dp.off + 4*SS];
        }
    }

    // ===== zero bitmap while loads are in flight (uint4: 2 iters) =====
    const uint4 z4 = {0u,0u,0u,0u};
    #pragma unroll
    for (int i = tid; i < NO_TOT/16; i += 256) rem4[i] = z4;
    __syncthreads();

    float lsum = 0.f;

    // ===== Phase 1: mark bitmap; coord loss once per batch (k==0) =====
    if (p1 && dp.valid) {
        removed[dp.now*SS + dp.cell] = 1;
        if (k == 0) {
            const float rax = 1.f/(1.f+expf(-e1));
            const float ray = 1.f/(1.f+expf(-e2));
            const float rw  = AW[dp.idx]*expf(e3);
            const float rh  = AH[dp.idx]*expf(e4);

            // iou_t with the reference's quirky formula (y1+1 inside the max)
            const float X1 = rax*DIVc - rw*0.5f, Y1 = ray*DIVc - rh*0.5f;
            const float X2 = rax*DIVc + rw*0.5f, Y2 = ray*DIVc + rh*0.5f;
            const float x1 = dp.ax*DIVc - dp.w*0.5f, y1 = dp.ay*DIVc - dp.h*0.5f;
            const float x2 = dp.ax*DIVc + dp.w*0.5f, y2 = dp.ay*DIVc + dp.h*0.5f;
            const float Bv  = (dp.w+1.f)*(dp.h+1.f);
            const float A2  = (rw+1.f)*(rh+1.f);
            const float CM2 = (fminf(X2,x2)-fmaxf(X1,x1)+1.f) *
                              (fminf(Y2,y2)-fmaxf(Y1,y1+1.f));
            const float iou_t = CM2/(A2+Bv-CM2);

            const float q0 = e0-iou_t, q1 = rax-dp.ax, q2 = ray-dp.ay,
                        q3 = rw-dp.w,  q4 = rh-dp.h;
            lsum += 5.f*q0*q0 + q1*q1 + q2*q2 + q3*q3 + q4*q4;
        }
    }

    // ===== Phase 2: BCE from prefetched v0/v1 (independent of bitmap) =====
    if (d0.valid) {
        const float label = 1.f/(1.f+expf(-v0));
        const float term = (cls0 == c0) ? fmaxf(logf(label),    -100.f)
                                        : fmaxf(log1pf(-label), -100.f);
        lsum -= term * (1.f/(float)Cc);
    }
    if (has1 && d1.valid) {
        const float label = 1.f/(1.f+expf(-v1));
        const float term = (cls1 == c1) ? fmaxf(logf(label),    -100.f)
                                        : fmaxf(log1pf(-label), -100.f);
        lsum -= term * (1.f/(float)Cc);
    }

    __syncthreads();   // bitmap complete

    // ===== Phase 3: noobj num (prefetched) + full-bitmap count =====
    float num = 0.f;
    #pragma unroll
    for (int i = 0; i < 4; ++i)
        if (pm[i] && !removed[tix[i]]) num += pre[i]*pre[i];

    int cnt = 0;
    #pragma unroll
    for (int i = tid; i < NO_TOT/16; i += 256) {
        const uint4 wd = rem4[i];
        const unsigned s = ((wd.x * 0x01010101u) >> 24)
                         + ((wd.y * 0x01010101u) >> 24)
                         + ((wd.z * 0x01010101u) >> 24)
                         + ((wd.w * 0x01010101u) >> 24);
        cnt += (int)s;
    }

    // ===== block reduce via shuffles; plain store (no atomics) =====
    #pragma unroll
    for (int o = 32; o > 0; o >>= 1) {
        lsum += __shfl_down(lsum, o);
        num  += __shfl_down(num,  o);
        cnt  += __shfl_down(cnt,  o);
    }
    const int wv = tid >> 6;
    if ((tid & 63) == 0) { wsf[wv] = lsum; wsn[wv] = num; wsc[wv] = cnt; }
    __syncthreads();
    if (tid == 0) {
        const float F  = wsf[0]+wsf[1]+wsf[2]+wsf[3];
        const float Nn = wsn[0]+wsn[1]+wsn[2]+wsn[3];
        const int   Ct = wsc[0]+wsc[1]+wsc[2]+wsc[3];
        partial[blk] = F + 0.5f * Nn / (float)(NO_TOT - Ct);
    }
}

// 1 block, 256 threads: deterministic fixed-order 512 -> 1 reduce.
__global__ __launch_bounds__(256) void yolo_finish(
    const float* __restrict__ partial, float* __restrict__ out)
{
    const int tid = threadIdx.x;
    __shared__ float ws[4];
    float v = partial[tid] + partial[tid + 256];
    #pragma unroll
    for (int o = 32; o > 0; o >>= 1) v += __shfl_down(v, o);
    if ((tid & 63) == 0) ws[tid >> 6] = v;
    __syncthreads();
    if (tid == 0) out[0] = ws[0] + ws[1] + ws[2] + ws[3];
}

extern "C" void kernel_launch(void* const* d_in, const int* in_sizes, int n_in,
                              void* d_out, int out_size, void* d_ws, size_t ws_size,
                              hipStream_t stream) {
    const float*  x    = (const float*)d_in[0];
    const float4* geo4 = (const float4*)d_in[1];
    const int*    cls  = (const int*)d_in[2];
    float* out     = (float*)d_out;
    float* partial = (float*)d_ws;     // NBLK floats, fully overwritten each call

    yolo_main<<<NBLK, 256, 0, stream>>>(x, geo4, cls, partial);
    yolo_finish<<<1, 256, 0, stream>>>(partial, out);
}